// Round 1
// baseline (393.306 us; speedup 1.0000x reference)
//
#include <hip/hip_runtime.h>

typedef __attribute__((ext_vector_type(8))) short bf16x8;
typedef __attribute__((ext_vector_type(4))) float f32x4;
typedef unsigned short u16;
typedef unsigned int u32;

#define DEV __device__ __forceinline__

DEV u16 f2bf(float f) {
  u32 u = __float_as_uint(f);
  u = u + 0x7FFFu + ((u >> 16) & 1u);
  return (u16)(u >> 16);
}
DEV float bf2f(u16 h) { return __uint_as_float(((u32)h) << 16); }
DEV u32 pack2(u16 a, u16 b) { return (u32)a | ((u32)b << 16); }

typedef __attribute__((address_space(1))) const u32 ASG_u32;
typedef __attribute__((address_space(3))) u32 ASL_u32;
DEV void gload16(const void* g, void* l) {
  __builtin_amdgcn_global_load_lds((ASG_u32*)g, (ASL_u32*)l, 16, 0, 0);
}

// ---------------- kernel 1: split x (fp32 -> bf16 hi/lo) ----------------
__global__ __launch_bounds__(256) void k_split_x(const float* __restrict__ x,
                                                 u16* __restrict__ xh,
                                                 u16* __restrict__ xl) {
  const size_t i = ((size_t)blockIdx.x * 256 + threadIdx.x) * 8;
  float4 a = *(const float4*)(x + i);
  float4 c = *(const float4*)(x + i + 4);
  float f[8] = {a.x, a.y, a.z, a.w, c.x, c.y, c.z, c.w};
  u16 hh[8], ll[8];
#pragma unroll
  for (int j = 0; j < 8; ++j) {
    hh[j] = f2bf(f[j]);
    ll[j] = f2bf(f[j] - bf2f(hh[j]));
  }
  uint4 uh, ul;
  uh.x = pack2(hh[0], hh[1]); uh.y = pack2(hh[2], hh[3]);
  uh.z = pack2(hh[4], hh[5]); uh.w = pack2(hh[6], hh[7]);
  ul.x = pack2(ll[0], ll[1]); ul.y = pack2(ll[2], ll[3]);
  ul.z = pack2(ll[4], ll[5]); ul.w = pack2(ll[6], ll[7]);
  *(uint4*)(xh + i) = uh;
  *(uint4*)(xl + i) = ul;
}

// ------------- kernel 2: transpose + split W -> Wt[w][h][d][1024] -------------
__global__ __launch_bounds__(256) void k_prep_w(const float* __restrict__ Wq,
                                                const float* __restrict__ Wk,
                                                const float* __restrict__ Wv,
                                                u16* __restrict__ wth,
                                                u16* __restrict__ wtl) {
  __shared__ float tile[64][65];
  const int bx = blockIdx.x;        // 0..767
  const int w = bx >> 8;            // 0..2
  const int rem = bx & 255;
  const int h = rem >> 4;           // 0..15
  const int nc = rem & 15;          // 0..15 (64-wide chunk of d_model)
  const float* W = (w == 0) ? Wq : ((w == 1) ? Wk : Wv);
  const int t = threadIdx.x;

  {
    const int r = t >> 2;
    const int cc = (t & 3) * 16;
    const float* src = W + ((size_t)h * 1024 + nc * 64 + r) * 64 + cc;
#pragma unroll
    for (int j = 0; j < 4; ++j) {
      float4 v = *(const float4*)(src + j * 4);
      tile[r][cc + j * 4 + 0] = v.x;
      tile[r][cc + j * 4 + 1] = v.y;
      tile[r][cc + j * 4 + 2] = v.z;
      tile[r][cc + j * 4 + 3] = v.w;
    }
  }
  __syncthreads();
  {
    const int d = t >> 2;
    const int n0 = (t & 3) * 16;
    u16 hh[16], ll[16];
#pragma unroll
    for (int n = 0; n < 16; ++n) {
      float f = tile[n0 + n][d];
      hh[n] = f2bf(f);
      ll[n] = f2bf(f - bf2f(hh[n]));
    }
    const size_t base = ((size_t)(w * 16 + h) * 64 + d) * 1024 + nc * 64 + n0;
    uint4 u0, u1, v0, v1;
    u0.x = pack2(hh[0], hh[1]);  u0.y = pack2(hh[2], hh[3]);
    u0.z = pack2(hh[4], hh[5]);  u0.w = pack2(hh[6], hh[7]);
    u1.x = pack2(hh[8], hh[9]);  u1.y = pack2(hh[10], hh[11]);
    u1.z = pack2(hh[12], hh[13]); u1.w = pack2(hh[14], hh[15]);
    v0.x = pack2(ll[0], ll[1]);  v0.y = pack2(ll[2], ll[3]);
    v0.z = pack2(ll[4], ll[5]);  v0.w = pack2(ll[6], ll[7]);
    v1.x = pack2(ll[8], ll[9]);  v1.y = pack2(ll[10], ll[11]);
    v1.z = pack2(ll[12], ll[13]); v1.w = pack2(ll[14], ll[15]);
    *(uint4*)(wth + base) = u0;
    *(uint4*)(wth + base + 8) = u1;
    *(uint4*)(wtl + base) = v0;
    *(uint4*)(wtl + base + 8) = v1;
  }
}

// ------------- kernel 3: projection GEMM (split precision for Q,K) -------------
// C[8192 x 3072] = x[8192 x 1024] @ W, tiles 128x64, per-head column blocks.
__global__ __launch_bounds__(256, 2) void k_proj(
    const u16* __restrict__ xh, const u16* __restrict__ xl,
    const u16* __restrict__ wth, const u16* __restrict__ wtl,
    u16* __restrict__ Qh, u16* __restrict__ Ql,
    u16* __restrict__ Kh, u16* __restrict__ Kl,
    u16* __restrict__ Vt) {
  __shared__ __align__(16) u16 lds[24576];  // Ah 16K | Al 16K | Bh 8K | Bl 8K bytes
  const int bx = blockIdx.x;
  const int bm = bx / 48;
  const int bn = bx % 48;
  const int w = bn >> 4;
  const int h = bn & 15;
  const bool isV = (w == 2);
  const int t = threadIdx.x;
  const int wave = t >> 6;
  const int lane = t & 63;
  const int wr = wave >> 1;
  const int wc = wave & 1;

  f32x4 acc[4][2];
#pragma unroll
  for (int mi = 0; mi < 4; ++mi)
#pragma unroll
    for (int ni = 0; ni < 2; ++ni) acc[mi][ni] = (f32x4)(0.0f);

  char* ldsb = (char*)lds;

  for (int kt = 0; kt < 16; ++kt) {
    const int k0 = kt * 64;
#pragma unroll
    for (int i = 0; i < 4; ++i) {
      const int ci = wave * 4 + i;                 // 0..15
      const int row = ci * 8 + (lane >> 3);        // 0..127
      const int cb = ((lane & 7) * 16) ^ ((row & 7) << 4);
      const size_t gb = ((size_t)(bm * 128 + row) * 1024 + k0) * 2;
      gload16((const char*)xh + gb + cb, ldsb + ci * 1024);
      if (!isV) gload16((const char*)xl + gb + cb, ldsb + 16384 + ci * 1024);
    }
#pragma unroll
    for (int i = 0; i < 2; ++i) {
      const int ci = wave * 2 + i;                 // 0..7
      const int row = ci * 8 + (lane >> 3);        // 0..63
      const int cb = ((lane & 7) * 16) ^ ((row & 7) << 4);
      const size_t gb = ((size_t)(bn * 64 + row) * 1024 + k0) * 2;
      gload16((const char*)wth + gb + cb, ldsb + 32768 + ci * 1024);
      if (!isV) gload16((const char*)wtl + gb + cb, ldsb + 40960 + ci * 1024);
    }
    __syncthreads();

#pragma unroll
    for (int ks = 0; ks < 2; ++ks) {
      bf16x8 ah[4], al[4], bh[2], bl[2];
#pragma unroll
      for (int mi = 0; mi < 4; ++mi) {
        const int row = wr * 64 + mi * 16 + (lane & 15);
        const int cb = (((lane >> 4) * 16) + ks * 64) ^ ((row & 7) << 4);
        ah[mi] = *(const bf16x8*)(ldsb + row * 128 + cb);
        if (!isV) al[mi] = *(const bf16x8*)(ldsb + 16384 + row * 128 + cb);
      }
#pragma unroll
      for (int ni = 0; ni < 2; ++ni) {
        const int row = wc * 32 + ni * 16 + (lane & 15);
        const int cb = (((lane >> 4) * 16) + ks * 64) ^ ((row & 7) << 4);
        bh[ni] = *(const bf16x8*)(ldsb + 32768 + row * 128 + cb);
        if (!isV) bl[ni] = *(const bf16x8*)(ldsb + 40960 + row * 128 + cb);
      }
#pragma unroll
      for (int mi = 0; mi < 4; ++mi)
#pragma unroll
        for (int ni = 0; ni < 2; ++ni) {
          acc[mi][ni] = __builtin_amdgcn_mfma_f32_16x16x32_bf16(ah[mi], bh[ni], acc[mi][ni], 0, 0, 0);
          if (!isV) {
            acc[mi][ni] = __builtin_amdgcn_mfma_f32_16x16x32_bf16(ah[mi], bl[ni], acc[mi][ni], 0, 0, 0);
            acc[mi][ni] = __builtin_amdgcn_mfma_f32_16x16x32_bf16(al[mi], bh[ni], acc[mi][ni], 0, 0, 0);
          }
        }
    }
    __syncthreads();
  }

  // epilogue
  const int rb = bm * 128 + wr * 64;
#pragma unroll
  for (int mi = 0; mi < 4; ++mi) {
#pragma unroll
    for (int ni = 0; ni < 2; ++ni) {
      f32x4 v = acc[mi][ni];
      const int d = wc * 32 + ni * 16 + (lane & 15);
      const int m0 = rb + mi * 16 + ((lane >> 4) << 2);
      const int b = m0 >> 11;
      const int ml = m0 & 2047;
      if (isV) {
        uint2 u;
        u.x = pack2(f2bf(v[0]), f2bf(v[1]));
        u.y = pack2(f2bf(v[2]), f2bf(v[3]));
        *(uint2*)(Vt + ((size_t)((b * 16 + h) * 64 + d)) * 2048 + ml) = u;
      } else {
        const float sc = (w == 0) ? 0.125f : 1.0f;  // fold 1/sqrt(64) into Q
        u16* AH = (w == 0) ? Qh : Kh;
        u16* AL = (w == 0) ? Ql : Kl;
#pragma unroll
        for (int j = 0; j < 4; ++j) {
          const float f = v[j] * sc;
          const u16 hi = f2bf(f);
          const u16 lo = f2bf(f - bf2f(hi));
          const size_t idx = ((size_t)(b * 16 + h) * 2048 + (ml + j)) * 64 + d;
          AH[idx] = hi;
          AL[idx] = lo;
        }
      }
    }
  }
}

// ---------------- kernel 4: flash attention ----------------
__global__ __launch_bounds__(256, 2) void k_attn(
    const u16* __restrict__ Qh, const u16* __restrict__ Ql,
    const u16* __restrict__ Kh, const u16* __restrict__ Kl,
    const u16* __restrict__ Vt, float* __restrict__ out) {
  __shared__ __align__(16) u16 lds[21504];  // Kh 8K | Kl 8K | Vt 8K bytes | P 4x4608B
  const int bx = blockIdx.x;
  const int bh = bx >> 4;
  const int qt = bx & 15;
  const int b = bh >> 4;
  const int h = bh & 15;
  const int t = threadIdx.x;
  const int wave = t >> 6;
  const int lane = t & 63;
  char* ldsb = (char*)lds;
  u16* sP = lds + 12288 + wave * 2304;  // per-wave 32x64 P, row stride 72 elems
  const char* sPb = (const char*)sP;

  bf16x8 qh[2][2], ql[2][2];
  const size_t qbase = ((size_t)bh * 2048 + qt * 128 + wave * 32) * 64;
#pragma unroll
  for (int mf = 0; mf < 2; ++mf)
#pragma unroll
    for (int ks = 0; ks < 2; ++ks) {
      const size_t off = qbase + (size_t)(mf * 16 + (lane & 15)) * 64 + ks * 32 + (lane >> 4) * 8;
      qh[mf][ks] = *(const bf16x8*)(Qh + off);
      ql[mf][ks] = *(const bf16x8*)(Ql + off);
    }

  f32x4 o[2][4];
  float ms[2][4], ls[2][4];
#pragma unroll
  for (int mf = 0; mf < 2; ++mf)
#pragma unroll
    for (int j = 0; j < 4; ++j) { ms[mf][j] = -1e30f; ls[mf][j] = 0.0f; }
#pragma unroll
  for (int mf = 0; mf < 2; ++mf)
#pragma unroll
    for (int df = 0; df < 4; ++df) o[mf][df] = (f32x4)(0.0f);

  const size_t kvbase = (size_t)bh * 2048 * 64;

  for (int kt = 0; kt < 32; ++kt) {
#pragma unroll
    for (int i = 0; i < 2; ++i) {
      const int ci = wave * 2 + i;            // 0..7
      const int row = ci * 8 + (lane >> 3);   // 0..63
      const int cb = ((lane & 7) * 16) ^ ((row & 7) << 4);
      const size_t gk = (kvbase + (size_t)(kt * 64 + row) * 64) * 2;
      gload16((const char*)Kh + gk + cb, ldsb + ci * 1024);
      gload16((const char*)Kl + gk + cb, ldsb + 8192 + ci * 1024);
      const size_t gv = (kvbase + (size_t)row * 2048 + kt * 64) * 2;
      gload16((const char*)Vt + gv + cb, ldsb + 16384 + ci * 1024);
    }
    __syncthreads();

    f32x4 s[2][4];
#pragma unroll
    for (int mf = 0; mf < 2; ++mf)
#pragma unroll
      for (int nf = 0; nf < 4; ++nf) s[mf][nf] = (f32x4)(0.0f);
#pragma unroll
    for (int ks = 0; ks < 2; ++ks) {
      bf16x8 kh2[4], kl2[4];
#pragma unroll
      for (int nf = 0; nf < 4; ++nf) {
        const int row = nf * 16 + (lane & 15);
        const int cb = (((lane >> 4) * 16) + ks * 64) ^ ((row & 7) << 4);
        kh2[nf] = *(const bf16x8*)(ldsb + row * 128 + cb);
        kl2[nf] = *(const bf16x8*)(ldsb + 8192 + row * 128 + cb);
      }
#pragma unroll
      for (int mf = 0; mf < 2; ++mf)
#pragma unroll
        for (int nf = 0; nf < 4; ++nf) {
          s[mf][nf] = __builtin_amdgcn_mfma_f32_16x16x32_bf16(qh[mf][ks], kh2[nf], s[mf][nf], 0, 0, 0);
          s[mf][nf] = __builtin_amdgcn_mfma_f32_16x16x32_bf16(qh[mf][ks], kl2[nf], s[mf][nf], 0, 0, 0);
          s[mf][nf] = __builtin_amdgcn_mfma_f32_16x16x32_bf16(ql[mf][ks], kh2[nf], s[mf][nf], 0, 0, 0);
        }
    }

    // online softmax (rows live on 16-lane groups) + P -> LDS (padded, bf16)
#pragma unroll
    for (int mf = 0; mf < 2; ++mf) {
#pragma unroll
      for (int j = 0; j < 4; ++j) {
        float v0 = s[mf][0][j], v1 = s[mf][1][j], v2 = s[mf][2][j], v3 = s[mf][3][j];
        float rm = fmaxf(fmaxf(v0, v1), fmaxf(v2, v3));
        rm = fmaxf(rm, __shfl_xor(rm, 1));
        rm = fmaxf(rm, __shfl_xor(rm, 2));
        rm = fmaxf(rm, __shfl_xor(rm, 4));
        rm = fmaxf(rm, __shfl_xor(rm, 8));
        const float mold = ms[mf][j];
        const float mnew = fmaxf(mold, rm);
        const float alpha = __expf(mold - mnew);
        const float p0 = __expf(v0 - mnew);
        const float p1 = __expf(v1 - mnew);
        const float p2 = __expf(v2 - mnew);
        const float p3 = __expf(v3 - mnew);
        float rs = p0 + p1 + p2 + p3;
        rs += __shfl_xor(rs, 1);
        rs += __shfl_xor(rs, 2);
        rs += __shfl_xor(rs, 4);
        rs += __shfl_xor(rs, 8);
        ls[mf][j] = ls[mf][j] * alpha + rs;
        ms[mf][j] = mnew;
#pragma unroll
        for (int df = 0; df < 4; ++df) o[mf][df][j] *= alpha;
        const int prow = mf * 16 + ((lane >> 4) << 2) + j;
        const int pc = lane & 15;
        sP[prow * 72 + pc] = f2bf(p0);
        sP[prow * 72 + pc + 16] = f2bf(p1);
        sP[prow * 72 + pc + 32] = f2bf(p2);
        sP[prow * 72 + pc + 48] = f2bf(p3);
      }
    }
    asm volatile("" ::: "memory");  // order P ds_writes before pa ds_reads

#pragma unroll
    for (int ks = 0; ks < 2; ++ks) {
      bf16x8 pa[2];
#pragma unroll
      for (int mf = 0; mf < 2; ++mf)
        pa[mf] = *(const bf16x8*)(sPb + (mf * 16 + (lane & 15)) * 144 + ks * 64 + (lane >> 4) * 16);
#pragma unroll
      for (int df = 0; df < 4; ++df) {
        const int row = df * 16 + (lane & 15);
        const int cb = (((lane >> 4) * 16) + ks * 64) ^ ((row & 7) << 4);
        const bf16x8 vb = *(const bf16x8*)(ldsb + 16384 + row * 128 + cb);
#pragma unroll
        for (int mf = 0; mf < 2; ++mf)
          o[mf][df] = __builtin_amdgcn_mfma_f32_16x16x32_bf16(pa[mf], vb, o[mf][df], 0, 0, 0);
      }
    }
    __syncthreads();
  }

#pragma unroll
  for (int mf = 0; mf < 2; ++mf)
#pragma unroll
    for (int j = 0; j < 4; ++j) {
      const float inv = 1.0f / ls[mf][j];
      const int m = qt * 128 + wave * 32 + mf * 16 + ((lane >> 4) << 2) + j;
#pragma unroll
      for (int df = 0; df < 4; ++df) {
        const int d = df * 16 + (lane & 15);
        out[((size_t)(b * 2048 + m)) * 1024 + h * 64 + d] = o[mf][df][j] * inv;
      }
    }
}

// ---------------- launch ----------------
extern "C" void kernel_launch(void* const* d_in, const int* in_sizes, int n_in,
                              void* d_out, int out_size, void* d_ws, size_t ws_size,
                              hipStream_t stream) {
  (void)in_sizes; (void)n_in; (void)out_size; (void)ws_size;
  const float* x  = (const float*)d_in[0];
  const float* Wq = (const float*)d_in[1];
  const float* Wk = (const float*)d_in[2];
  const float* Wv = (const float*)d_in[3];
  float* out = (float*)d_out;

  u16* ws = (u16*)d_ws;  // element (u16) offsets
  u16* xh  = ws + 0;            // 8192*1024
  u16* xl  = ws + 8388608;
  u16* wth = ws + 16777216;     // 3*16*64*1024
  u16* wtl = ws + 19922944;
  u16* Qh  = ws + 23068672;     // 64*2048*64 each
  u16* Ql  = ws + 31457280;
  u16* Kh  = ws + 39845888;
  u16* Kl  = ws + 48234496;
  u16* Vt  = ws + 56623104;     // [bh][64][2048]

  k_split_x<<<4096, 256, 0, stream>>>(x, xh, xl);
  k_prep_w<<<768, 256, 0, stream>>>(Wq, Wk, Wv, wth, wtl);
  k_proj<<<3072, 256, 0, stream>>>(xh, xl, wth, wtl, Qh, Ql, Kh, Kl, Vt);
  k_attn<<<1024, 256, 0, stream>>>(Qh, Ql, Kh, Kl, Vt, out);
}

// Round 2
// 326.674 us; speedup vs baseline: 1.2040x; 1.2040x over previous
//
#include <hip/hip_runtime.h>

typedef __attribute__((ext_vector_type(8))) _Float16 f16x8;
typedef __attribute__((ext_vector_type(4))) float f32x4;
typedef _Float16 f16;
typedef unsigned short u16;
typedef unsigned int u32;

#define DEV __device__ __forceinline__

DEV u32 packh2(float a, float b) {
  union { f16 h[2]; u32 u; } x;
  x.h[0] = (f16)a; x.h[1] = (f16)b;
  return x.u;
}

typedef __attribute__((address_space(1))) const u32 ASG_u32;
typedef __attribute__((address_space(3))) u32 ASL_u32;
DEV void gload16(const void* g, void* l) {
  __builtin_amdgcn_global_load_lds((ASG_u32*)g, (ASL_u32*)l, 16, 0, 0);
}

// ---------------- kernel 1: x (fp32 -> fp16) ----------------
__global__ __launch_bounds__(256) void k_half_x(const float* __restrict__ x,
                                                f16* __restrict__ xh) {
  const size_t i = ((size_t)blockIdx.x * 256 + threadIdx.x) * 8;
  float4 a = *(const float4*)(x + i);
  float4 c = *(const float4*)(x + i + 4);
  uint4 u;
  u.x = packh2(a.x, a.y); u.y = packh2(a.z, a.w);
  u.z = packh2(c.x, c.y); u.w = packh2(c.z, c.w);
  *(uint4*)(xh + i) = u;
}

// ------------- kernel 2: transpose W -> Wt[w][h][d][1024] fp16 -------------
__global__ __launch_bounds__(256) void k_prep_w(const float* __restrict__ Wq,
                                                const float* __restrict__ Wk,
                                                const float* __restrict__ Wv,
                                                f16* __restrict__ wt) {
  __shared__ float tile[64][65];
  const int bx = blockIdx.x;        // 0..767
  const int w = bx >> 8;
  const int rem = bx & 255;
  const int h = rem >> 4;
  const int nc = rem & 15;          // 64-wide chunk of d_model
  const float* W = (w == 0) ? Wq : ((w == 1) ? Wk : Wv);
  const int t = threadIdx.x;

  {
    const int r = t >> 2;
    const int cc = (t & 3) * 16;
    const float* src = W + ((size_t)h * 1024 + nc * 64 + r) * 64 + cc;
#pragma unroll
    for (int j = 0; j < 4; ++j) {
      float4 v = *(const float4*)(src + j * 4);
      tile[r][cc + j * 4 + 0] = v.x;
      tile[r][cc + j * 4 + 1] = v.y;
      tile[r][cc + j * 4 + 2] = v.z;
      tile[r][cc + j * 4 + 3] = v.w;
    }
  }
  __syncthreads();
  {
    const int d = t >> 2;
    const int n0 = (t & 3) * 16;
    const size_t base = ((size_t)(w * 16 + h) * 64 + d) * 1024 + nc * 64 + n0;
    uint4 u0, u1;
    u0.x = packh2(tile[n0 + 0][d], tile[n0 + 1][d]);
    u0.y = packh2(tile[n0 + 2][d], tile[n0 + 3][d]);
    u0.z = packh2(tile[n0 + 4][d], tile[n0 + 5][d]);
    u0.w = packh2(tile[n0 + 6][d], tile[n0 + 7][d]);
    u1.x = packh2(tile[n0 + 8][d], tile[n0 + 9][d]);
    u1.y = packh2(tile[n0 + 10][d], tile[n0 + 11][d]);
    u1.z = packh2(tile[n0 + 12][d], tile[n0 + 13][d]);
    u1.w = packh2(tile[n0 + 14][d], tile[n0 + 15][d]);
    *(uint4*)(wt + base) = u0;
    *(uint4*)(wt + base + 8) = u1;
  }
}

// ------------- kernel 3: projection GEMM (fp16) -------------
// C[8192 x 3072] = x[8192 x 1024] @ W; tiles 128x64 per (128-row, head*type) block.
__global__ __launch_bounds__(256, 4) void k_proj(
    const f16* __restrict__ xh, const f16* __restrict__ wt,
    f16* __restrict__ Q, f16* __restrict__ K, f16* __restrict__ Vt) {
  __shared__ __align__(16) char ldsb[24576];  // A 16K | B 8K
  const int bx = blockIdx.x;
  const int bm = bx / 48;
  const int bn = bx % 48;
  const int w = bn >> 4;
  const int h = bn & 15;
  const bool isV = (w == 2);
  const int t = threadIdx.x;
  const int wave = t >> 6;
  const int lane = t & 63;
  const int wr = wave >> 1;
  const int wc = wave & 1;

  f32x4 acc[4][2];
#pragma unroll
  for (int mi = 0; mi < 4; ++mi)
#pragma unroll
    for (int ni = 0; ni < 2; ++ni) acc[mi][ni] = (f32x4)(0.0f);

  for (int kt = 0; kt < 16; ++kt) {
    const int k0 = kt * 64;
#pragma unroll
    for (int i = 0; i < 4; ++i) {
      const int ci = wave * 4 + i;                 // 0..15
      const int row = ci * 8 + (lane >> 3);        // 0..127
      const int cb = ((lane & 7) * 16) ^ ((row & 7) << 4);
      const size_t gb = ((size_t)(bm * 128 + row) * 1024 + k0) * 2;
      gload16((const char*)xh + gb + cb, ldsb + ci * 1024);
    }
#pragma unroll
    for (int i = 0; i < 2; ++i) {
      const int ci = wave * 2 + i;                 // 0..7
      const int row = ci * 8 + (lane >> 3);        // 0..63
      const int cb = ((lane & 7) * 16) ^ ((row & 7) << 4);
      const size_t gb = ((size_t)(bn * 64 + row) * 1024 + k0) * 2;
      gload16((const char*)wt + gb + cb, ldsb + 16384 + ci * 1024);
    }
    __syncthreads();

#pragma unroll
    for (int ks = 0; ks < 2; ++ks) {
      f16x8 af[4], bf[2];
#pragma unroll
      for (int mi = 0; mi < 4; ++mi) {
        const int row = wr * 64 + mi * 16 + (lane & 15);
        const int cb = (((lane >> 4) * 16) + ks * 64) ^ ((row & 7) << 4);
        af[mi] = *(const f16x8*)(ldsb + row * 128 + cb);
      }
#pragma unroll
      for (int ni = 0; ni < 2; ++ni) {
        const int row = wc * 32 + ni * 16 + (lane & 15);
        const int cb = (((lane >> 4) * 16) + ks * 64) ^ ((row & 7) << 4);
        bf[ni] = *(const f16x8*)(ldsb + 16384 + row * 128 + cb);
      }
#pragma unroll
      for (int mi = 0; mi < 4; ++mi)
#pragma unroll
        for (int ni = 0; ni < 2; ++ni)
          acc[mi][ni] = __builtin_amdgcn_mfma_f32_16x16x32_f16(af[mi], bf[ni], acc[mi][ni], 0, 0, 0);
    }
    __syncthreads();
  }

  // epilogue
  const int rb = bm * 128 + wr * 64;
#pragma unroll
  for (int mi = 0; mi < 4; ++mi) {
#pragma unroll
    for (int ni = 0; ni < 2; ++ni) {
      f32x4 v = acc[mi][ni];
      const int d = wc * 32 + ni * 16 + (lane & 15);
      const int m0 = rb + mi * 16 + ((lane >> 4) << 2);
      const int b = m0 >> 11;
      const int ml = m0 & 2047;
      if (isV) {
        uint2 u;
        u.x = packh2(v[0], v[1]);
        u.y = packh2(v[2], v[3]);
        *(uint2*)(Vt + ((size_t)((b * 16 + h) * 64 + d)) * 2048 + ml) = u;
      } else {
        const float sc = (w == 0) ? 0.125f : 1.0f;  // fold 1/sqrt(64) into Q
        f16* A = (w == 0) ? Q : K;
#pragma unroll
        for (int j = 0; j < 4; ++j)
          A[((size_t)(b * 16 + h) * 2048 + (ml + j)) * 64 + d] = (f16)(v[j] * sc);
      }
    }
  }
}

// ---------------- kernel 4: flash attention (fp16) ----------------
__global__ __launch_bounds__(256, 4) void k_attn(
    const f16* __restrict__ Q, const f16* __restrict__ K,
    const f16* __restrict__ Vt, float* __restrict__ out) {
  __shared__ __align__(16) char ldsb[34816];  // K 8K | Vt 8K | P 4x4608B
  const int bx = blockIdx.x;
  const int bh = bx >> 4;
  const int qt = bx & 15;
  const int b = bh >> 4;
  const int h = bh & 15;
  const int t = threadIdx.x;
  const int wave = t >> 6;
  const int lane = t & 63;
  f16* sP = (f16*)(ldsb + 16384 + wave * 4608);  // per-wave 32x64 P, row stride 72 elems
  const char* sPb = (const char*)sP;

  f16x8 qf[2][2];
  const size_t qbase = ((size_t)bh * 2048 + qt * 128 + wave * 32) * 64;
#pragma unroll
  for (int mf = 0; mf < 2; ++mf)
#pragma unroll
    for (int ks = 0; ks < 2; ++ks) {
      const size_t off = qbase + (size_t)(mf * 16 + (lane & 15)) * 64 + ks * 32 + (lane >> 4) * 8;
      qf[mf][ks] = *(const f16x8*)(Q + off);
    }

  f32x4 o[2][4];
  float ms[2][4], ls[2][4];
#pragma unroll
  for (int mf = 0; mf < 2; ++mf)
#pragma unroll
    for (int j = 0; j < 4; ++j) { ms[mf][j] = -1e30f; ls[mf][j] = 0.0f; }
#pragma unroll
  for (int mf = 0; mf < 2; ++mf)
#pragma unroll
    for (int df = 0; df < 4; ++df) o[mf][df] = (f32x4)(0.0f);

  const size_t kvbase = (size_t)bh * 2048 * 64;

  for (int kt = 0; kt < 32; ++kt) {
#pragma unroll
    for (int i = 0; i < 2; ++i) {
      const int ci = wave * 2 + i;            // 0..7
      const int row = ci * 8 + (lane >> 3);   // 0..63
      const int cb = ((lane & 7) * 16) ^ ((row & 7) << 4);
      const size_t gk = (kvbase + (size_t)(kt * 64 + row) * 64) * 2;
      gload16((const char*)K + gk + cb, ldsb + ci * 1024);
      const size_t gv = (kvbase + (size_t)row * 2048 + kt * 64) * 2;
      gload16((const char*)Vt + gv + cb, ldsb + 8192 + ci * 1024);
    }
    __syncthreads();

    f32x4 s[2][4];
#pragma unroll
    for (int mf = 0; mf < 2; ++mf)
#pragma unroll
      for (int nf = 0; nf < 4; ++nf) s[mf][nf] = (f32x4)(0.0f);
#pragma unroll
    for (int ks = 0; ks < 2; ++ks) {
      f16x8 kf[4];
#pragma unroll
      for (int nf = 0; nf < 4; ++nf) {
        const int row = nf * 16 + (lane & 15);
        const int cb = (((lane >> 4) * 16) + ks * 64) ^ ((row & 7) << 4);
        kf[nf] = *(const f16x8*)(ldsb + row * 128 + cb);
      }
#pragma unroll
      for (int mf = 0; mf < 2; ++mf)
#pragma unroll
        for (int nf = 0; nf < 4; ++nf)
          s[mf][nf] = __builtin_amdgcn_mfma_f32_16x16x32_f16(qf[mf][ks], kf[nf], s[mf][nf], 0, 0, 0);
    }

    // online softmax (rows live on 16-lane groups) + P -> LDS (padded, fp16)
#pragma unroll
    for (int mf = 0; mf < 2; ++mf) {
#pragma unroll
      for (int j = 0; j < 4; ++j) {
        float v0 = s[mf][0][j], v1 = s[mf][1][j], v2 = s[mf][2][j], v3 = s[mf][3][j];
        float rm = fmaxf(fmaxf(v0, v1), fmaxf(v2, v3));
        rm = fmaxf(rm, __shfl_xor(rm, 1));
        rm = fmaxf(rm, __shfl_xor(rm, 2));
        rm = fmaxf(rm, __shfl_xor(rm, 4));
        rm = fmaxf(rm, __shfl_xor(rm, 8));
        const float mold = ms[mf][j];
        const float mnew = fmaxf(mold, rm);
        const float alpha = __expf(mold - mnew);
        const float p0 = __expf(v0 - mnew);
        const float p1 = __expf(v1 - mnew);
        const float p2 = __expf(v2 - mnew);
        const float p3 = __expf(v3 - mnew);
        float rs = p0 + p1 + p2 + p3;
        rs += __shfl_xor(rs, 1);
        rs += __shfl_xor(rs, 2);
        rs += __shfl_xor(rs, 4);
        rs += __shfl_xor(rs, 8);
        ls[mf][j] = ls[mf][j] * alpha + rs;
        ms[mf][j] = mnew;
#pragma unroll
        for (int df = 0; df < 4; ++df) o[mf][df][j] *= alpha;
        const int prow = mf * 16 + ((lane >> 4) << 2) + j;
        const int pc = lane & 15;
        sP[prow * 72 + pc] = (f16)p0;
        sP[prow * 72 + pc + 16] = (f16)p1;
        sP[prow * 72 + pc + 32] = (f16)p2;
        sP[prow * 72 + pc + 48] = (f16)p3;
      }
    }
    asm volatile("" ::: "memory");  // order P ds_writes before pa ds_reads

#pragma unroll
    for (int ks = 0; ks < 2; ++ks) {
      f16x8 pa[2];
#pragma unroll
      for (int mf = 0; mf < 2; ++mf)
        pa[mf] = *(const f16x8*)(sPb + (mf * 16 + (lane & 15)) * 144 + ks * 64 + (lane >> 4) * 16);
#pragma unroll
      for (int df = 0; df < 4; ++df) {
        const int row = df * 16 + (lane & 15);
        const int cb = (((lane >> 4) * 16) + ks * 64) ^ ((row & 7) << 4);
        const f16x8 vb = *(const f16x8*)(ldsb + 8192 + row * 128 + cb);
#pragma unroll
        for (int mf = 0; mf < 2; ++mf)
          o[mf][df] = __builtin_amdgcn_mfma_f32_16x16x32_f16(pa[mf], vb, o[mf][df], 0, 0, 0);
      }
    }
    __syncthreads();
  }

#pragma unroll
  for (int mf = 0; mf < 2; ++mf)
#pragma unroll
    for (int j = 0; j < 4; ++j) {
      const float inv = 1.0f / ls[mf][j];
      const int m = qt * 128 + wave * 32 + mf * 16 + ((lane >> 4) << 2) + j;
#pragma unroll
      for (int df = 0; df < 4; ++df) {
        const int d = df * 16 + (lane & 15);
        out[((size_t)(b * 2048 + m)) * 1024 + h * 64 + d] = o[mf][df][j] * inv;
      }
    }
}

// ---------------- launch ----------------
extern "C" void kernel_launch(void* const* d_in, const int* in_sizes, int n_in,
                              void* d_out, int out_size, void* d_ws, size_t ws_size,
                              hipStream_t stream) {
  (void)in_sizes; (void)n_in; (void)out_size; (void)ws_size;
  const float* x  = (const float*)d_in[0];
  const float* Wq = (const float*)d_in[1];
  const float* Wk = (const float*)d_in[2];
  const float* Wv = (const float*)d_in[3];
  float* out = (float*)d_out;

  f16* ws = (f16*)d_ws;  // element (f16) offsets
  f16* xh = ws + 0;            // 8192*1024
  f16* wt = ws + 8388608;      // 3*16*64*1024
  f16* Q  = ws + 11534336;     // 64*2048*64 each
  f16* K  = ws + 19922944;
  f16* Vt = ws + 28311552;     // [bh][64][2048]

  k_half_x<<<4096, 256, 0, stream>>>(x, xh);
  k_prep_w<<<768, 256, 0, stream>>>(Wq, Wk, Wv, wt);
  k_proj<<<3072, 256, 0, stream>>>(xh, wt, Q, K, Vt);
  k_attn<<<1024, 256, 0, stream>>>(Q, K, Vt, out);
}

// Round 3
// 261.202 us; speedup vs baseline: 1.5058x; 1.2507x over previous
//
#include <hip/hip_runtime.h>

typedef __attribute__((ext_vector_type(8))) _Float16 f16x8;
typedef __attribute__((ext_vector_type(4))) float f32x4;
typedef _Float16 f16;
typedef unsigned short u16;
typedef unsigned int u32;

#define DEV __device__ __forceinline__

DEV u32 packh2(float a, float b) {
  union { f16 h[2]; u32 u; } x;
  x.h[0] = (f16)a; x.h[1] = (f16)b;
  return x.u;
}

typedef __attribute__((address_space(1))) const u32 ASG_u32;
typedef __attribute__((address_space(3))) u32 ASL_u32;
DEV void gload16(const void* g, void* l) {
  __builtin_amdgcn_global_load_lds((ASG_u32*)g, (ASL_u32*)l, 16, 0, 0);
}

// ---------------- kernel 1: x (fp32 -> fp16) ----------------
__global__ __launch_bounds__(256) void k_half_x(const float* __restrict__ x,
                                                f16* __restrict__ xh) {
  const size_t i = ((size_t)blockIdx.x * 256 + threadIdx.x) * 8;
  float4 a = *(const float4*)(x + i);
  float4 c = *(const float4*)(x + i + 4);
  uint4 u;
  u.x = packh2(a.x, a.y); u.y = packh2(a.z, a.w);
  u.z = packh2(c.x, c.y); u.w = packh2(c.z, c.w);
  *(uint4*)(xh + i) = u;
}

// ------------- kernel 2: transpose W -> Wt[w][h][d][1024] fp16 -------------
__global__ __launch_bounds__(256) void k_prep_w(const float* __restrict__ Wq,
                                                const float* __restrict__ Wk,
                                                const float* __restrict__ Wv,
                                                f16* __restrict__ wt) {
  __shared__ float tile[64][65];
  const int bx = blockIdx.x;        // 0..767
  const int w = bx >> 8;
  const int rem = bx & 255;
  const int h = rem >> 4;
  const int nc = rem & 15;          // 64-wide chunk of d_model
  const float* W = (w == 0) ? Wq : ((w == 1) ? Wk : Wv);
  const int t = threadIdx.x;

  {
    const int r = t >> 2;
    const int cc = (t & 3) * 16;
    const float* src = W + ((size_t)h * 1024 + nc * 64 + r) * 64 + cc;
#pragma unroll
    for (int j = 0; j < 4; ++j) {
      float4 v = *(const float4*)(src + j * 4);
      tile[r][cc + j * 4 + 0] = v.x;
      tile[r][cc + j * 4 + 1] = v.y;
      tile[r][cc + j * 4 + 2] = v.z;
      tile[r][cc + j * 4 + 3] = v.w;
    }
  }
  __syncthreads();
  {
    const int d = t >> 2;
    const int n0 = (t & 3) * 16;
    const size_t base = ((size_t)(w * 16 + h) * 64 + d) * 1024 + nc * 64 + n0;
    uint4 u0, u1;
    u0.x = packh2(tile[n0 + 0][d], tile[n0 + 1][d]);
    u0.y = packh2(tile[n0 + 2][d], tile[n0 + 3][d]);
    u0.z = packh2(tile[n0 + 4][d], tile[n0 + 5][d]);
    u0.w = packh2(tile[n0 + 6][d], tile[n0 + 7][d]);
    u1.x = packh2(tile[n0 + 8][d], tile[n0 + 9][d]);
    u1.y = packh2(tile[n0 + 10][d], tile[n0 + 11][d]);
    u1.z = packh2(tile[n0 + 12][d], tile[n0 + 13][d]);
    u1.w = packh2(tile[n0 + 14][d], tile[n0 + 15][d]);
    *(uint4*)(wt + base) = u0;
    *(uint4*)(wt + base + 8) = u1;
  }
}

// ------------- kernel 3: projection GEMM (fp16) -------------
__global__ __launch_bounds__(256, 4) void k_proj(
    const f16* __restrict__ xh, const f16* __restrict__ wt,
    f16* __restrict__ Q, f16* __restrict__ K, f16* __restrict__ Vt) {
  __shared__ __align__(16) char ldsb[24576];  // A 16K | B 8K
  int bid = blockIdx.x;
  bid = (bid & 7) * 384 + (bid >> 3);  // XCD swizzle (3072 % 8 == 0, bijective)
  const int bm = bid / 48;
  const int bn = bid % 48;
  const int w = bn >> 4;
  const int h = bn & 15;
  const bool isV = (w == 2);
  const int t = threadIdx.x;
  const int wave = t >> 6;
  const int lane = t & 63;
  const int wr = wave >> 1;
  const int wc = wave & 1;

  f32x4 acc[4][2];
#pragma unroll
  for (int mi = 0; mi < 4; ++mi)
#pragma unroll
    for (int ni = 0; ni < 2; ++ni) acc[mi][ni] = (f32x4)(0.0f);

  for (int kt = 0; kt < 16; ++kt) {
    const int k0 = kt * 64;
#pragma unroll
    for (int i = 0; i < 4; ++i) {
      const int ci = wave * 4 + i;                 // 0..15
      const int row = ci * 8 + (lane >> 3);        // 0..127
      const int cb = ((lane & 7) * 16) ^ ((row & 7) << 4);
      const size_t gb = ((size_t)(bm * 128 + row) * 1024 + k0) * 2;
      gload16((const char*)xh + gb + cb, ldsb + ci * 1024);
    }
#pragma unroll
    for (int i = 0; i < 2; ++i) {
      const int ci = wave * 2 + i;                 // 0..7
      const int row = ci * 8 + (lane >> 3);        // 0..63
      const int cb = ((lane & 7) * 16) ^ ((row & 7) << 4);
      const size_t gb = ((size_t)(bn * 64 + row) * 1024 + k0) * 2;
      gload16((const char*)wt + gb + cb, ldsb + 16384 + ci * 1024);
    }
    __syncthreads();

#pragma unroll
    for (int ks = 0; ks < 2; ++ks) {
      f16x8 af[4], bfr[2];
#pragma unroll
      for (int mi = 0; mi < 4; ++mi) {
        const int row = wr * 64 + mi * 16 + (lane & 15);
        const int cb = (((lane >> 4) * 16) + ks * 64) ^ ((row & 7) << 4);
        af[mi] = *(const f16x8*)(ldsb + row * 128 + cb);
      }
#pragma unroll
      for (int ni = 0; ni < 2; ++ni) {
        const int row = wc * 32 + ni * 16 + (lane & 15);
        const int cb = (((lane >> 4) * 16) + ks * 64) ^ ((row & 7) << 4);
        bfr[ni] = *(const f16x8*)(ldsb + 16384 + row * 128 + cb);
      }
#pragma unroll
      for (int mi = 0; mi < 4; ++mi)
#pragma unroll
        for (int ni = 0; ni < 2; ++ni)
          acc[mi][ni] = __builtin_amdgcn_mfma_f32_16x16x32_f16(af[mi], bfr[ni], acc[mi][ni], 0, 0, 0);
    }
    __syncthreads();
  }

  // epilogue
  const int rb = bm * 128 + wr * 64;
#pragma unroll
  for (int mi = 0; mi < 4; ++mi) {
#pragma unroll
    for (int ni = 0; ni < 2; ++ni) {
      f32x4 v = acc[mi][ni];
      const int d = wc * 32 + ni * 16 + (lane & 15);
      const int m0 = rb + mi * 16 + ((lane >> 4) << 2);
      const int b = m0 >> 11;
      const int ml = m0 & 2047;
      if (isV) {
        uint2 u;
        u.x = packh2(v[0], v[1]);
        u.y = packh2(v[2], v[3]);
        *(uint2*)(Vt + ((size_t)((b * 16 + h) * 64 + d)) * 2048 + ml) = u;
      } else {
        const float sc = (w == 0) ? 0.125f : 1.0f;  // fold 1/sqrt(64) into Q
        f16* A = (w == 0) ? Q : K;
#pragma unroll
        for (int j = 0; j < 4; ++j)
          A[((size_t)(b * 16 + h) * 2048 + (ml + j)) * 64 + d] = (f16)(v[j] * sc);
      }
    }
  }
}

// ---------------- kernel 4: flash attention (fp16, dbuf, defer-max) ----------------
__global__ __launch_bounds__(256, 3) void k_attn(
    const f16* __restrict__ Q, const f16* __restrict__ K,
    const f16* __restrict__ Vt, float* __restrict__ out) {
  // LDS: 2 x (K 8K | Vt 8K) dbuf = 32K, then P 4 x 4608B
  __shared__ __align__(16) char ldsb[51200];
  int bid = blockIdx.x;
  bid = (bid & 7) * 128 + (bid >> 3);  // XCD swizzle (1024 % 8 == 0, bijective)
  const int bh = bid >> 4;
  const int qt = bid & 15;
  const int b = bh >> 4;
  const int h = bh & 15;
  const int t = threadIdx.x;
  const int wave = t >> 6;
  const int lane = t & 63;
  f16* sP = (f16*)(ldsb + 32768 + wave * 4608);  // per-wave 32x64 P, row stride 72 elems
  const char* sPb = (const char*)sP;

  f16x8 qf[2][2];
  const size_t qbase = ((size_t)bh * 2048 + qt * 128 + wave * 32) * 64;
#pragma unroll
  for (int mf = 0; mf < 2; ++mf)
#pragma unroll
    for (int ks = 0; ks < 2; ++ks) {
      const size_t off = qbase + (size_t)(mf * 16 + (lane & 15)) * 64 + ks * 32 + (lane >> 4) * 8;
      qf[mf][ks] = *(const f16x8*)(Q + off);
    }

  f32x4 o[2][4];
  float ms[2][4], ls[2][4];
#pragma unroll
  for (int mf = 0; mf < 2; ++mf)
#pragma unroll
    for (int j = 0; j < 4; ++j) { ms[mf][j] = -1e30f; ls[mf][j] = 0.0f; }
#pragma unroll
  for (int mf = 0; mf < 2; ++mf)
#pragma unroll
    for (int df = 0; df < 4; ++df) o[mf][df] = (f32x4)(0.0f);

  const size_t kvbase = (size_t)bh * 2048 * 64;

  // per-thread staging addresses (hoisted)
  const int srow = (wave * 2) * 8 + (lane >> 3);     // rows for i=0; i=1 adds 8
  const int scb0 = ((lane & 7) * 16) ^ ((srow & 7) << 4);  // row&7 same for row and row+8

#pragma unroll 1
  for (int kt = 0; kt < 33; ++kt) {
    // stage tile kt into buf kt&1 (issued one iteration ahead of use)
    if (kt < 32) {
      char* dst = ldsb + (kt & 1) * 16384;
#pragma unroll
      for (int i = 0; i < 2; ++i) {
        const int ci = wave * 2 + i;
        const int row = srow + i * 8;
        const size_t gk = (kvbase + (size_t)(kt * 64 + row) * 64) * 2;
        gload16((const char*)K + gk + scb0, dst + ci * 1024);
        const size_t gv = (kvbase + (size_t)row * 2048 + kt * 64) * 2;
        gload16((const char*)Vt + gv + scb0, dst + 8192 + ci * 1024);
      }
    }
    if (kt == 0) { __syncthreads(); continue; }
    const int ct = kt - 1;              // compute tile
    const char* kb = ldsb + (ct & 1) * 16384;
    const char* vbuf = kb + 8192;

    f32x4 s[2][4];
#pragma unroll
    for (int mf = 0; mf < 2; ++mf)
#pragma unroll
      for (int nf = 0; nf < 4; ++nf) s[mf][nf] = (f32x4)(0.0f);
#pragma unroll
    for (int ks = 0; ks < 2; ++ks) {
      f16x8 kf[4];
#pragma unroll
      for (int nf = 0; nf < 4; ++nf) {
        const int row = nf * 16 + (lane & 15);
        const int cb = (((lane >> 4) * 16) + ks * 64) ^ ((row & 7) << 4);
        kf[nf] = *(const f16x8*)(kb + row * 128 + cb);
      }
#pragma unroll
      for (int mf = 0; mf < 2; ++mf)
#pragma unroll
        for (int nf = 0; nf < 4; ++nf)
          s[mf][nf] = __builtin_amdgcn_mfma_f32_16x16x32_f16(qf[mf][ks], kf[nf], s[mf][nf], 0, 0, 0);
    }

    // online softmax: row lives on a 16-lane group; defer-max (THR=8), per-lane partial l
#pragma unroll
    for (int mf = 0; mf < 2; ++mf) {
#pragma unroll
      for (int j = 0; j < 4; ++j) {
        float v0 = s[mf][0][j], v1 = s[mf][1][j], v2 = s[mf][2][j], v3 = s[mf][3][j];
        float rm = fmaxf(fmaxf(v0, v1), fmaxf(v2, v3));
        rm = fmaxf(rm, __shfl_xor(rm, 1));
        rm = fmaxf(rm, __shfl_xor(rm, 2));
        rm = fmaxf(rm, __shfl_xor(rm, 4));
        rm = fmaxf(rm, __shfl_xor(rm, 8));
        if (rm > ms[mf][j] + 8.0f) {      // rescale only on significant max growth
          const float alpha = __expf(ms[mf][j] - rm);
          ms[mf][j] = rm;
          ls[mf][j] *= alpha;
#pragma unroll
          for (int df = 0; df < 4; ++df) o[mf][df][j] *= alpha;
        }
        const float mnew = ms[mf][j];
        const float p0 = __expf(v0 - mnew);
        const float p1 = __expf(v1 - mnew);
        const float p2 = __expf(v2 - mnew);
        const float p3 = __expf(v3 - mnew);
        ls[mf][j] += (p0 + p1) + (p2 + p3);   // per-lane partial; reduced once at end
        const int prow = mf * 16 + ((lane >> 4) << 2) + j;
        const int pc = lane & 15;
        sP[prow * 72 + pc] = (f16)p0;
        sP[prow * 72 + pc + 16] = (f16)p1;
        sP[prow * 72 + pc + 32] = (f16)p2;
        sP[prow * 72 + pc + 48] = (f16)p3;
      }
    }
    asm volatile("" ::: "memory");  // order P ds_writes before pa ds_reads

#pragma unroll
    for (int ks = 0; ks < 2; ++ks) {
      f16x8 pa[2];
#pragma unroll
      for (int mf = 0; mf < 2; ++mf)
        pa[mf] = *(const f16x8*)(sPb + (mf * 16 + (lane & 15)) * 144 + ks * 64 + (lane >> 4) * 16);
#pragma unroll
      for (int df = 0; df < 4; ++df) {
        const int row = df * 16 + (lane & 15);
        const int cb = (((lane >> 4) * 16) + ks * 64) ^ ((row & 7) << 4);
        const f16x8 vb = *(const f16x8*)(vbuf + row * 128 + cb);
#pragma unroll
        for (int mf = 0; mf < 2; ++mf)
          o[mf][df] = __builtin_amdgcn_mfma_f32_16x16x32_f16(pa[mf], vb, o[mf][df], 0, 0, 0);
      }
    }
    __syncthreads();  // publishes buf (kt&1) staged this iteration; guards reuse
  }

#pragma unroll
  for (int mf = 0; mf < 2; ++mf)
#pragma unroll
    for (int j = 0; j < 4; ++j) {
      float l = ls[mf][j];
      l += __shfl_xor(l, 1);
      l += __shfl_xor(l, 2);
      l += __shfl_xor(l, 4);
      l += __shfl_xor(l, 8);
      const float inv = 1.0f / l;
      const int m = qt * 128 + wave * 32 + mf * 16 + ((lane >> 4) << 2) + j;
#pragma unroll
      for (int df = 0; df < 4; ++df) {
        const int d = df * 16 + (lane & 15);
        out[((size_t)(b * 2048 + m)) * 1024 + h * 64 + d] = o[mf][df][j] * inv;
      }
    }
}

// ---------------- launch ----------------
extern "C" void kernel_launch(void* const* d_in, const int* in_sizes, int n_in,
                              void* d_out, int out_size, void* d_ws, size_t ws_size,
                              hipStream_t stream) {
  (void)in_sizes; (void)n_in; (void)out_size; (void)ws_size;
  const float* x  = (const float*)d_in[0];
  const float* Wq = (const float*)d_in[1];
  const float* Wk = (const float*)d_in[2];
  const float* Wv = (const float*)d_in[3];
  float* out = (float*)d_out;

  f16* ws = (f16*)d_ws;  // element (f16) offsets
  f16* xh = ws + 0;            // 8192*1024
  f16* wt = ws + 8388608;      // 3*16*64*1024
  f16* Q  = ws + 11534336;     // 64*2048*64 each
  f16* K  = ws + 19922944;
  f16* Vt = ws + 28311552;     // [bh][64][2048]

  k_half_x<<<4096, 256, 0, stream>>>(x, xh);
  k_prep_w<<<768, 256, 0, stream>>>(Wq, Wk, Wv, wt);
  k_proj<<<3072, 256, 0, stream>>>(xh, wt, Q, K, Vt);
  k_attn<<<1024, 256, 0, stream>>>(Q, K, Vt, out);
}

// Round 5
// 194.719 us; speedup vs baseline: 2.0199x; 1.3414x over previous
//
#include <hip/hip_runtime.h>

typedef __attribute__((ext_vector_type(8))) _Float16 f16x8;
typedef __attribute__((ext_vector_type(2))) __fp16 fp16v2;
typedef __attribute__((ext_vector_type(4))) float f32x4;
typedef _Float16 f16;
typedef unsigned short u16;
typedef unsigned int u32;

#define DEV __device__ __forceinline__

DEV u32 packh2(float a, float b) {
  union { f16 h[2]; u32 u; } x;
  x.h[0] = (f16)a; x.h[1] = (f16)b;
  return x.u;
}
DEV u32 pkrtz(float a, float b) {
  union { fp16v2 h; u32 u; } x;
  x.h = __builtin_amdgcn_cvt_pkrtz(a, b);
  return x.u;
}
DEV float exp2_fast(float x) {
  float r;
  asm("v_exp_f32 %0, %1" : "=v"(r) : "v"(x));
  return r;
}

typedef __attribute__((address_space(1))) const u32 ASG_u32;
typedef __attribute__((address_space(3))) u32 ASL_u32;
DEV void gload16(const void* g, void* l) {
  __builtin_amdgcn_global_load_lds((ASG_u32*)g, (ASL_u32*)l, 16, 0, 0);
}

// ---------------- kernel 1: x (fp32 -> fp16) ----------------
__global__ __launch_bounds__(256) void k_half_x(const float* __restrict__ x,
                                                f16* __restrict__ xh) {
  const size_t i = ((size_t)blockIdx.x * 256 + threadIdx.x) * 8;
  float4 a = *(const float4*)(x + i);
  float4 c = *(const float4*)(x + i + 4);
  uint4 u;
  u.x = packh2(a.x, a.y); u.y = packh2(a.z, a.w);
  u.z = packh2(c.x, c.y); u.w = packh2(c.z, c.w);
  *(uint4*)(xh + i) = u;
}

// ------------- kernel 2: transpose W -> Wt[w][h][d][1024] fp16 -------------
__global__ __launch_bounds__(256) void k_prep_w(const float* __restrict__ Wq,
                                                const float* __restrict__ Wk,
                                                const float* __restrict__ Wv,
                                                f16* __restrict__ wt) {
  __shared__ float tile[64][65];
  const int bx = blockIdx.x;        // 0..767
  const int w = bx >> 8;
  const int rem = bx & 255;
  const int h = rem >> 4;
  const int nc = rem & 15;          // 64-wide chunk of d_model
  const float* W = (w == 0) ? Wq : ((w == 1) ? Wk : Wv);
  const int t = threadIdx.x;

  {
    const int r = t >> 2;
    const int cc = (t & 3) * 16;
    const float* src = W + ((size_t)h * 1024 + nc * 64 + r) * 64 + cc;
#pragma unroll
    for (int j = 0; j < 4; ++j) {
      float4 v = *(const float4*)(src + j * 4);
      tile[r][cc + j * 4 + 0] = v.x;
      tile[r][cc + j * 4 + 1] = v.y;
      tile[r][cc + j * 4 + 2] = v.z;
      tile[r][cc + j * 4 + 3] = v.w;
    }
  }
  __syncthreads();
  {
    const int d = t >> 2;
    const int n0 = (t & 3) * 16;
    const size_t base = ((size_t)(w * 16 + h) * 64 + d) * 1024 + nc * 64 + n0;
    uint4 u0, u1;
    u0.x = packh2(tile[n0 + 0][d], tile[n0 + 1][d]);
    u0.y = packh2(tile[n0 + 2][d], tile[n0 + 3][d]);
    u0.z = packh2(tile[n0 + 4][d], tile[n0 + 5][d]);
    u0.w = packh2(tile[n0 + 6][d], tile[n0 + 7][d]);
    u1.x = packh2(tile[n0 + 8][d], tile[n0 + 9][d]);
    u1.y = packh2(tile[n0 + 10][d], tile[n0 + 11][d]);
    u1.z = packh2(tile[n0 + 12][d], tile[n0 + 13][d]);
    u1.w = packh2(tile[n0 + 14][d], tile[n0 + 15][d]);
    *(uint4*)(wt + base) = u0;
    *(uint4*)(wt + base + 8) = u1;
  }
}

// ------------- kernel 3: projection GEMM (fp16) -------------
__global__ __launch_bounds__(256, 4) void k_proj(
    const f16* __restrict__ xh, const f16* __restrict__ wt,
    f16* __restrict__ Q, f16* __restrict__ K, f16* __restrict__ Vt) {
  __shared__ __align__(16) char ldsb[24576];  // A 16K | B 8K
  int bid = blockIdx.x;
  bid = (bid & 7) * 384 + (bid >> 3);  // XCD swizzle (3072 % 8 == 0, bijective)
  const int bm = bid / 48;
  const int bn = bid % 48;
  const int w = bn >> 4;
  const int h = bn & 15;
  const bool isV = (w == 2);
  const int t = threadIdx.x;
  const int wave = t >> 6;
  const int lane = t & 63;
  const int wr = wave >> 1;
  const int wc = wave & 1;

  f32x4 acc[4][2];
#pragma unroll
  for (int mi = 0; mi < 4; ++mi)
#pragma unroll
    for (int ni = 0; ni < 2; ++ni) acc[mi][ni] = (f32x4)(0.0f);

  for (int kt = 0; kt < 16; ++kt) {
    const int k0 = kt * 64;
#pragma unroll
    for (int i = 0; i < 4; ++i) {
      const int ci = wave * 4 + i;                 // 0..15
      const int row = ci * 8 + (lane >> 3);        // 0..127
      const int cb = ((lane & 7) * 16) ^ ((row & 7) << 4);
      const size_t gb = ((size_t)(bm * 128 + row) * 1024 + k0) * 2;
      gload16((const char*)xh + gb + cb, ldsb + ci * 1024);
    }
#pragma unroll
    for (int i = 0; i < 2; ++i) {
      const int ci = wave * 2 + i;                 // 0..7
      const int row = ci * 8 + (lane >> 3);        // 0..63
      const int cb = ((lane & 7) * 16) ^ ((row & 7) << 4);
      const size_t gb = ((size_t)(bn * 64 + row) * 1024 + k0) * 2;
      gload16((const char*)wt + gb + cb, ldsb + 16384 + ci * 1024);
    }
    __syncthreads();

#pragma unroll
    for (int ks = 0; ks < 2; ++ks) {
      f16x8 af[4], bfr[2];
#pragma unroll
      for (int mi = 0; mi < 4; ++mi) {
        const int row = wr * 64 + mi * 16 + (lane & 15);
        const int cb = (((lane >> 4) * 16) + ks * 64) ^ ((row & 7) << 4);
        af[mi] = *(const f16x8*)(ldsb + row * 128 + cb);
      }
#pragma unroll
      for (int ni = 0; ni < 2; ++ni) {
        const int row = wc * 32 + ni * 16 + (lane & 15);
        const int cb = (((lane >> 4) * 16) + ks * 64) ^ ((row & 7) << 4);
        bfr[ni] = *(const f16x8*)(ldsb + 16384 + row * 128 + cb);
      }
#pragma unroll
      for (int mi = 0; mi < 4; ++mi)
#pragma unroll
        for (int ni = 0; ni < 2; ++ni)
          acc[mi][ni] = __builtin_amdgcn_mfma_f32_16x16x32_f16(af[mi], bfr[ni], acc[mi][ni], 0, 0, 0);
    }
    __syncthreads();
  }

  // epilogue
  const int rb = bm * 128 + wr * 64;
#pragma unroll
  for (int mi = 0; mi < 4; ++mi) {
#pragma unroll
    for (int ni = 0; ni < 2; ++ni) {
      f32x4 v = acc[mi][ni];
      const int d = wc * 32 + ni * 16 + (lane & 15);
      const int m0 = rb + mi * 16 + ((lane >> 4) << 2);
      const int b = m0 >> 11;
      const int ml = m0 & 2047;
      if (isV) {
        uint2 u;
        u.x = packh2(v[0], v[1]);
        u.y = packh2(v[2], v[3]);
        *(uint2*)(Vt + ((size_t)((b * 16 + h) * 64 + d)) * 2048 + ml) = u;
      } else {
        // Q: fold 1/sqrt(64) AND log2(e) (softmax done in exp2 domain)
        const float sc = (w == 0) ? 0.18033688f : 1.0f;
        f16* A = (w == 0) ? Q : K;
#pragma unroll
        for (int j = 0; j < 4; ++j)
          A[((size_t)(b * 16 + h) * 2048 + (ml + j)) * 64 + d] = (f16)(v[j] * sc);
      }
    }
  }
}

// ------- kernel 4: flash attention (swapped QK^T, lane-local softmax) -------
__global__ __launch_bounds__(256, 3) void k_attn(
    const f16* __restrict__ Q, const f16* __restrict__ K,
    const f16* __restrict__ Vt, float* __restrict__ out) {
  // LDS: 2 x (K 8K | Vt 8K) dbuf = 32K | P 4 x 4096B
  __shared__ __align__(16) char ldsb[49152];
  int bid = blockIdx.x;
  bid = (bid & 7) * 128 + (bid >> 3);  // XCD swizzle (1024 % 8 == 0, bijective)
  const int bh = bid >> 4;
  const int qt = bid & 15;
  const int b = bh >> 4;
  const int h = bh & 15;
  const int t = threadIdx.x;
  const int wave = t >> 6;
  const int lane = t & 63;
  const int l15 = lane & 15;
  const int g = lane >> 4;
  char* sP = ldsb + 32768 + wave * 4096;  // per-wave P[32 rows][128 B], XOR-swizzled

  f16x8 qf[2][2];
  const size_t qbase = ((size_t)bh * 2048 + qt * 128 + wave * 32) * 64;
#pragma unroll
  for (int mf = 0; mf < 2; ++mf)
#pragma unroll
    for (int ks = 0; ks < 2; ++ks) {
      const size_t off = qbase + (size_t)(mf * 16 + l15) * 64 + ks * 32 + g * 8;
      qf[mf][ks] = *(const f16x8*)(Q + off);
    }

  f32x4 o[2][4];
  float ms[2], ls[2];
#pragma unroll
  for (int mf = 0; mf < 2; ++mf) { ms[mf] = -1e30f; ls[mf] = 0.0f; }
#pragma unroll
  for (int mf = 0; mf < 2; ++mf)
#pragma unroll
    for (int df = 0; df < 4; ++df) o[mf][df] = (f32x4)(0.0f);

  const size_t kvbase = (size_t)bh * 2048 * 64;

  // per-thread staging addresses (hoisted)
  const int srow = (wave * 2) * 8 + (lane >> 3);           // rows for i=0; i=1 adds 8
  const int scb0 = ((lane & 7) * 16) ^ ((srow & 7) << 4);  // row&7 same for row, row+8

#pragma unroll 1
  for (int kt = 0; kt < 33; ++kt) {
    // stage tile kt into buf kt&1 (issued one iteration ahead of use)
    if (kt < 32) {
      char* dst = ldsb + (kt & 1) * 16384;
#pragma unroll
      for (int i = 0; i < 2; ++i) {
        const int ci = wave * 2 + i;
        const int row = srow + i * 8;
        const size_t gk = (kvbase + (size_t)(kt * 64 + row) * 64) * 2;
        gload16((const char*)K + gk + scb0, dst + ci * 1024);
        const size_t gv = (kvbase + (size_t)row * 2048 + kt * 64) * 2;
        gload16((const char*)Vt + gv + scb0, dst + 8192 + ci * 1024);
      }
    }
    if (kt == 0) { __syncthreads(); continue; }
    const char* kb = ldsb + ((kt - 1) & 1) * 16384;
    const char* vbuf = kb + 8192;

    // S^T = mfma(K_frag, Q_frag): lane holds, per mf, 16 k-values of q = mf*16+l15
    f32x4 st[2][4];
#pragma unroll
    for (int mf = 0; mf < 2; ++mf)
#pragma unroll
      for (int nf = 0; nf < 4; ++nf) st[mf][nf] = (f32x4)(0.0f);
#pragma unroll
    for (int ks = 0; ks < 2; ++ks) {
      f16x8 kf[4];
#pragma unroll
      for (int nf = 0; nf < 4; ++nf) {
        const int row = nf * 16 + l15;
        const int cb = ((g * 16) + ks * 64) ^ ((row & 7) << 4);
        kf[nf] = *(const f16x8*)(kb + row * 128 + cb);
      }
#pragma unroll
      for (int mf = 0; mf < 2; ++mf)
#pragma unroll
        for (int nf = 0; nf < 4; ++nf)
          st[mf][nf] = __builtin_amdgcn_mfma_f32_16x16x32_f16(kf[nf], qf[mf][ks], st[mf][nf], 0, 0, 0);
    }

    // lane-local online softmax (logits are in log2 domain; Q pre-scaled)
#pragma unroll
    for (int mf = 0; mf < 2; ++mf) {
      float rm = fmaxf(fmaxf(fmaxf(st[mf][0][0], st[mf][0][1]), fmaxf(st[mf][0][2], st[mf][0][3])),
                       fmaxf(fmaxf(st[mf][1][0], st[mf][1][1]), fmaxf(st[mf][1][2], st[mf][1][3])));
      rm = fmaxf(rm, fmaxf(fmaxf(fmaxf(st[mf][2][0], st[mf][2][1]), fmaxf(st[mf][2][2], st[mf][2][3])),
                           fmaxf(fmaxf(st[mf][3][0], st[mf][3][1]), fmaxf(st[mf][3][2], st[mf][3][3]))));
      rm = fmaxf(rm, __shfl_xor(rm, 16));
      rm = fmaxf(rm, __shfl_xor(rm, 32));
      if (__any(rm > ms[mf] + 11.5f)) {   // defer-max (THR=8 in base-e)
        const float mnew = fmaxf(ms[mf], rm);
        const float alpha = exp2_fast(ms[mf] - mnew);
        ms[mf] = mnew;
        ls[mf] *= alpha;
        f32x4 av;
#pragma unroll
        for (int j = 0; j < 4; ++j) av[j] = __shfl(alpha, g * 4 + j);
#pragma unroll
        for (int df = 0; df < 4; ++df) o[mf][df] *= av;
      }
      const float m = ms[mf];
      float p[4][4], part = 0.0f;
#pragma unroll
      for (int nf = 0; nf < 4; ++nf) {
#pragma unroll
        for (int j = 0; j < 4; ++j) {
          p[nf][j] = exp2_fast(st[mf][nf][j] - m);
          part += p[nf][j];
        }
      }
      ls[mf] += part;
      const int prow = mf * 16 + l15;
      char* pr = sP + prow * 128;
      const int swz = (prow & 7) << 4;
#pragma unroll
      for (int nf = 0; nf < 4; ++nf) {
        uint2 u;
        u.x = pkrtz(p[nf][0], p[nf][1]);
        u.y = pkrtz(p[nf][2], p[nf][3]);
        *(uint2*)(pr + (((nf << 5) + (g << 3)) ^ swz)) = u;
      }
    }
    asm volatile("" ::: "memory");  // order P ds_writes before pa ds_reads

#pragma unroll
    for (int ks = 0; ks < 2; ++ks) {
      f16x8 pa[2];
#pragma unroll
      for (int mf = 0; mf < 2; ++mf) {
        const int prow = mf * 16 + l15;
        pa[mf] = *(const f16x8*)(sP + prow * 128 + ((ks * 64 + g * 16) ^ ((prow & 7) << 4)));
      }
#pragma unroll
      for (int df = 0; df < 4; ++df) {
        const int row = df * 16 + l15;
        const int cb = ((g * 16) + ks * 64) ^ ((row & 7) << 4);
        const f16x8 vb = *(const f16x8*)(vbuf + row * 128 + cb);
#pragma unroll
        for (int mf = 0; mf < 2; ++mf)
          o[mf][df] = __builtin_amdgcn_mfma_f32_16x16x32_f16(pa[mf], vb, o[mf][df], 0, 0, 0);
      }
    }
    __syncthreads();  // publishes buf staged this iteration; guards reuse
  }

  // epilogue: O fragment rows are q = mf*16 + g*4 + j; l lives at lane l15 == q
#pragma unroll
  for (int mf = 0; mf < 2; ++mf) {
    float l = ls[mf];
    l += __shfl_xor(l, 16);
    l += __shfl_xor(l, 32);
    const float inv = 1.0f / l;
    f32x4 iv;
#pragma unroll
    for (int j = 0; j < 4; ++j) iv[j] = __shfl(inv, g * 4 + j);
#pragma unroll
    for (int j = 0; j < 4; ++j) {
      const int m = qt * 128 + wave * 32 + mf * 16 + g * 4 + j;
#pragma unroll
      for (int df = 0; df < 4; ++df) {
        const int d = df * 16 + l15;
        out[((size_t)(b * 2048 + m)) * 1024 + h * 64 + d] = o[mf][df][j] * iv[j];
      }
    }
  }
}

// ---------------- launch ----------------
extern "C" void kernel_launch(void* const* d_in, const int* in_sizes, int n_in,
                              void* d_out, int out_size, void* d_ws, size_t ws_size,
                              hipStream_t stream) {
  (void)in_sizes; (void)n_in; (void)out_size; (void)ws_size;
  const float* x  = (const float*)d_in[0];
  const float* Wq = (const float*)d_in[1];
  const float* Wk = (const float*)d_in[2];
  const float* Wv = (const float*)d_in[3];
  float* out = (float*)d_out;

  f16* ws = (f16*)d_ws;  // element (f16) offsets
  f16* xh = ws + 0;            // 8192*1024
  f16* wt = ws + 8388608;      // 3*16*64*1024
  f16* Q  = ws + 11534336;     // 64*2048*64 each
  f16* K  = ws + 19922944;
  f16* Vt = ws + 28311552;     // [bh][64][2048]

  k_half_x<<<4096, 256, 0, stream>>>(x, xh);
  k_prep_w<<<768, 256, 0, stream>>>(Wq, Wk, Wv, wt);
  k_proj<<<3072, 256, 0, stream>>>(xh, wt, Q, K, Vt);
  k_attn<<<1024, 256, 0, stream>>>(Q, K, Vt, out);
}